// Round 8
// baseline (8093.271 us; speedup 1.0000x reference)
//
#include <hip/hip_runtime.h>
#include <math.h>

// ---------------------------------------------------------------------------
// Sizes (fixed by the problem)
//   input_context  [512][768]   output_context [1024][768]
//   fw_wih [1536][768] fw_whh [1536][512] fw_bih/bhh [1536]
//   bw_wih [1536][768] (whh unused: bwd_hs[-1] = one step from h0=0)
//   dec_wih [3072][768] dec_whh [3072][1024] dec_bih/bhh [3072]
//   W_pred [1024][28996]   out [1024][28996] fp32
// ---------------------------------------------------------------------------

typedef unsigned long long u64;
typedef unsigned short ushort_t;
typedef __attribute__((ext_vector_type(8))) short short8;   // 8 bf16 (4 VGPR)
typedef __attribute__((ext_vector_type(4))) float f32x4;

#define NWG 64
#define NT 512
#define NV 28996

__device__ __forceinline__ float sigmoidf_(float x) {
  return 1.0f / (1.0f + __expf(-x));
}
__device__ __forceinline__ float tanhf_(float x) {
  const float xx = fminf(fmaxf(x, -15.0f), 15.0f);
  const float e = __expf(2.0f * xx);
  return (e - 1.0f) / (e + 1.0f);
}
__device__ __forceinline__ ushort_t f2bf(float f) {
  union { float f; unsigned u; } c; c.f = f;
  unsigned u = c.u;
  u += 0x7fffu + ((u >> 16) & 1u);  // RNE
  return (ushort_t)(u >> 16);
}

// (tag, h) fused in one 8-byte word: single relaxed agent-scope atomic store
// publishes value + readiness together. Tags are the sole sync authority.
__device__ __forceinline__ u64 pack_ht(float h, unsigned tag) {
  union { float f; unsigned u; } c; c.f = h;
  return ((u64)tag << 32) | (u64)c.u;
}
__device__ __forceinline__ float pk_h(u64 v) {
  union { unsigned u; float f; } c; c.u = (unsigned)v; return c.f;
}
__device__ __forceinline__ void astore(u64* p, u64 v) {
  __hip_atomic_store(p, v, __ATOMIC_RELAXED, __HIP_MEMORY_SCOPE_AGENT);
}
__device__ __forceinline__ u64 aload(const u64* p) {
  return __hip_atomic_load((u64*)p, __ATOMIC_RELAXED, __HIP_MEMORY_SCOPE_AGENT);
}

// ---------------------------------------------------------------------------
// Persistent recurrence kernel. 64 wgs x 512 threads.
// BARRIER-FREE / LDS-FREE: every wave polls the full fused (tag,h) buffer
// into registers itself, computes its unit's dot product from registers,
// butterfly-reduces across 64 lanes, and publishes. No __syncthreads in the
// step loop; waves run independently, ordered only by tags.
//
// Ordering safety (per-wave depth-2): the published u64 packs h which is
// data-dependent on ALL polled h values of the previous step, so a store of
// tag t cannot retire before that wave's step-(t-1) poll loads completed.
// A wave overwrites slot s (parity p) with tag t+1 only after observing all
// slots at tag >= t; each tag-t publish implies its producer finished its
// step-(t-1) reads of slot s. Hence every reader of (s, tag t-1) is done
// before (s, tag t+1) lands. Weight/gx loads are issued BEFORE the poll so
// their L2 latency hides under the poll round trip (no pinning needed).
// ---------------------------------------------------------------------------
__global__ __launch_bounds__(NT, 2) void recur_kernel(
    const float* __restrict__ gxfw,    // [512][1536]
    const float* __restrict__ gxdec,   // [1024][3072]
    const float* __restrict__ gxbw,    // [1536]
    const float* __restrict__ whh_fw,  // [1536][512]
    const float* __restrict__ bhh_fw,  // [1536]
    const float* __restrict__ whh_dec, // [3072][1024]
    const float* __restrict__ bhh_dec, // [3072]
    const float* __restrict__ bhh_bw,  // [1536]
    u64* fwbuf,                        // [2][512]  zeroed: (h=0, tag=0)
    u64* decbuf,                       // [2][1024] zeroed
    float* __restrict__ dec_hs,        // [1024][1024] f32 (fallback GEMM)
    ushort_t* __restrict__ dec_hs_bf,  // [1024][1024] bf16 (MFMA GEMM)
    int do_bf16)
{
  const int tid = threadIdx.x;
  const int wg = blockIdx.x;
  const int wave = tid >> 6;
  const int lane = tid & 63;

  // backward "encoder" = one GRU cell on input row 511 from h0=0 (gh = bhh).
  // Written to decoder parity-0 slots 512..1023 with tag 512 (no ordering
  // needed vs fw: dec polls cover it).
  if (wg == 0) {
    const int j = tid;  // NT == 512 == HIDDEN
    const float r = sigmoidf_(gxbw[j] + bhh_bw[j]);
    const float z = sigmoidf_(gxbw[512 + j] + bhh_bw[512 + j]);
    const float n = tanhf_(gxbw[1024 + j] + r * bhh_bw[1024 + j]);
    astore(&decbuf[512 + j], pack_ht((1.0f - z) * n, 512u));
  }

  // ---------------- forward encoder: 512 steps ----------------
  {
    const int u = (wg << 3) + wave;      // 0..511, one unit per wave
    const int jmine = u >> 6;            // slot-group holding h[u]
    const int lmine = u & 63;            // lane holding h[u]
    const float br = bhh_fw[u], bz = bhh_fw[512 + u], bn = bhh_fw[1024 + u];
    const float* w0 = whh_fw + (size_t)u * 512 + lane;
    const float* w1 = whh_fw + (size_t)(512 + u) * 512 + lane;
    const float* w2 = whh_fw + (size_t)(1024 + u) * 512 + lane;
    for (int t = 0; t < 512; ++t) {
      const u64* src = fwbuf + ((t & 1) << 9);
      // weight + gx loads issued BEFORE the poll: latency hides under RTT
      float wv0[8], wv1[8], wv2[8];
#pragma unroll
      for (int j = 0; j < 8; ++j) {
        wv0[j] = w0[j << 6];
        wv1[j] = w1[j << 6];
        wv2[j] = w2[j << 6];
      }
      const float* gx = gxfw + (size_t)t * 1536;
      const float g0 = gx[u], g1 = gx[512 + u], g2 = gx[1024 + u];
      u64 v[8];
      for (;;) {  // all-wave direct poll (R2-form full re-read)
        bool ok = true;
#pragma unroll
        for (int j = 0; j < 8; ++j) {
          v[j] = aload(src + (j << 6) + lane);
          ok &= ((unsigned)(v[j] >> 32) >= (unsigned)t);
        }
        if (__all(ok)) break;
      }
      float p0 = 0.f, p1 = 0.f, p2 = 0.f, hml = 0.f;
#pragma unroll
      for (int j = 0; j < 8; ++j) {
        const float h = pk_h(v[j]);
        p0 += wv0[j] * h;
        p1 += wv1[j] * h;
        p2 += wv2[j] * h;
        if (j == jmine) hml = h;  // static index select (no scratch)
      }
#pragma unroll
      for (int s = 1; s < 64; s <<= 1) {
        p0 += __shfl_xor(p0, s, 64);
        p1 += __shfl_xor(p1, s, 64);
        p2 += __shfl_xor(p2, s, 64);
      }
      const float hold = __shfl(hml, lmine, 64);
      const float r = sigmoidf_(g0 + p0 + br);
      const float z = sigmoidf_(g1 + p1 + bz);
      const float n = tanhf_(g2 + r * (p2 + bn));
      const float hnew = (1.0f - z) * n + z * hold;
      if (lane == 0) {
        u64* dst = (t < 511) ? (fwbuf + (((t + 1) & 1) << 9) + u)
                             : (decbuf + u);  // parity 0, tag 512
        astore(dst, pack_ht(hnew, (unsigned)(t + 1)));
      }
    }
  }

  // ---------------- decoder: 1024 steps ----------------
  {
    const int u0 = (wg << 4) + (wave << 1);  // 2 units per wave
    const int jm0 = u0 >> 6, lm0 = u0 & 63;
    const int jm1 = (u0 + 1) >> 6, lm1 = (u0 + 1) & 63;
    const float b00 = bhh_dec[u0], b01 = bhh_dec[1024 + u0],
                b02 = bhh_dec[2048 + u0];
    const float b10 = bhh_dec[u0 + 1], b11 = bhh_dec[1024 + u0 + 1],
                b12 = bhh_dec[2048 + u0 + 1];
    const float* wa0 = whh_dec + (size_t)u0 * 1024 + lane;
    const float* wa1 = whh_dec + (size_t)(1024 + u0) * 1024 + lane;
    const float* wa2 = whh_dec + (size_t)(2048 + u0) * 1024 + lane;
    const float* wb0 = whh_dec + (size_t)(u0 + 1) * 1024 + lane;
    const float* wb1 = whh_dec + (size_t)(1024 + u0 + 1) * 1024 + lane;
    const float* wb2 = whh_dec + (size_t)(2048 + u0 + 1) * 1024 + lane;
    for (int td = 0; td < 1024; ++td) {
      const int t = 512 + td;  // global tag
      const u64* src = decbuf + ((t & 1) << 10);
      // weight + gx loads before the poll (L2 latency hidden)
      float va0[16], va1[16], va2[16], vb0[16], vb1[16], vb2[16];
#pragma unroll
      for (int j = 0; j < 16; ++j) {
        va0[j] = wa0[j << 6]; va1[j] = wa1[j << 6]; va2[j] = wa2[j << 6];
        vb0[j] = wb0[j << 6]; vb1[j] = wb1[j << 6]; vb2[j] = wb2[j << 6];
      }
      const float* gx = gxdec + (size_t)td * 3072;
      const float ga0 = gx[u0], ga1 = gx[1024 + u0], ga2 = gx[2048 + u0];
      const float gb0 = gx[u0 + 1], gb1 = gx[1024 + u0 + 1],
                  gb2 = gx[2048 + u0 + 1];
      u64 v[16];
      for (;;) {
        bool ok = true;
#pragma unroll
        for (int j = 0; j < 16; ++j) {
          v[j] = aload(src + (j << 6) + lane);
          ok &= ((unsigned)(v[j] >> 32) >= (unsigned)t);
        }
        if (__all(ok)) break;
      }
      float pa0 = 0.f, pa1 = 0.f, pa2 = 0.f;
      float pb0 = 0.f, pb1 = 0.f, pb2 = 0.f;
      float hm0 = 0.f, hm1 = 0.f;
#pragma unroll
      for (int j = 0; j < 16; ++j) {
        const float h = pk_h(v[j]);
        pa0 += va0[j] * h; pa1 += va1[j] * h; pa2 += va2[j] * h;
        pb0 += vb0[j] * h; pb1 += vb1[j] * h; pb2 += vb2[j] * h;
        if (j == jm0) hm0 = h;
        if (j == jm1) hm1 = h;
      }
#pragma unroll
      for (int s = 1; s < 64; s <<= 1) {
        pa0 += __shfl_xor(pa0, s, 64);
        pa1 += __shfl_xor(pa1, s, 64);
        pa2 += __shfl_xor(pa2, s, 64);
        pb0 += __shfl_xor(pb0, s, 64);
        pb1 += __shfl_xor(pb1, s, 64);
        pb2 += __shfl_xor(pb2, s, 64);
      }
      const float hold0 = __shfl(hm0, lm0, 64);
      const float hold1 = __shfl(hm1, lm1, 64);
      const float r0 = sigmoidf_(ga0 + pa0 + b00);
      const float z0 = sigmoidf_(ga1 + pa1 + b01);
      const float n0 = tanhf_(ga2 + r0 * (pa2 + b02));
      const float hn0 = (1.0f - z0) * n0 + z0 * hold0;
      const float r1 = sigmoidf_(gb0 + pb0 + b10);
      const float z1 = sigmoidf_(gb1 + pb1 + b11);
      const float n1 = tanhf_(gb2 + r1 * (pb2 + b12));
      const float hn1 = (1.0f - z1) * n1 + z1 * hold1;
      if (lane < 2) {  // one exec-masked 16B publish (2 adjacent u64)
        astore(decbuf + (((t + 1) & 1) << 10) + u0 + lane,
               pack_ht(lane ? hn1 : hn0, (unsigned)(t + 1)));
      }
      if (lane == 0) {  // output row (plain store, read by next kernel)
        if (do_bf16) {
          const unsigned pk =
              (unsigned)f2bf(hn0) | ((unsigned)f2bf(hn1) << 16);
          *(unsigned*)&dec_hs_bf[(size_t)td * 1024 + u0] = pk;
        } else {
          dec_hs[(size_t)td * 1024 + u0] = hn0;
          dec_hs[(size_t)td * 1024 + u0 + 1] = hn1;
        }
      }
    }
  }
}

// ---------------------------------------------------------------------------
// W_pred [1024][28996] f32  ->  Wt [28996][1024] bf16 (k-contiguous rows).
// ---------------------------------------------------------------------------
__global__ __launch_bounds__(256) void wt_transpose(
    const float* __restrict__ W, ushort_t* __restrict__ Wt) {
  __shared__ float T[64][65];
  const int tid = threadIdx.x;
  const int n0 = blockIdx.x * 64;
  const int k0 = blockIdx.y * 64;
  const int nloc = tid & 63;
  const int q = tid >> 6;  // 0..3
  const bool nok = (n0 + nloc) < NV;
#pragma unroll
  for (int r = 0; r < 16; ++r) {
    const int kloc = q + r * 4;
    T[kloc][nloc] = nok ? W[(size_t)(k0 + kloc) * NV + n0 + nloc] : 0.f;
  }
  __syncthreads();
  const int kloc2 = tid & 63;
#pragma unroll
  for (int w = 0; w < 16; ++w) {
    const int nloc2 = q + w * 4;
    if (n0 + nloc2 < NV)
      Wt[(size_t)(n0 + nloc2) * 1024 + k0 + kloc2] = f2bf(T[kloc2][nloc2]);
  }
}

// ---------------------------------------------------------------------------
// bf16 MFMA vocab GEMM: out[1024][28996] = dec_hs_bf x Wt^T.
// 128x128 tile, BK=64, 512 threads = 8 waves (4M x 2N), 16x16x32 MFMA.
// ---------------------------------------------------------------------------
__global__ __launch_bounds__(512) void gemm_vocab_bf16(
    const ushort_t* __restrict__ A,   // [1024][1024] bf16
    const ushort_t* __restrict__ Bt,  // [28996][1024] bf16
    float* __restrict__ C) {          // [1024][28996] f32
  __shared__ short As[128 * 72];
  __shared__ short Bs[128 * 72];
  const int tid = threadIdx.x;
  const int lane = tid & 63;
  const int wid = tid >> 6;
  const int wm = wid >> 1;   // 0..3
  const int wn = wid & 1;    // 0..1
  const int n0 = blockIdx.x * 128;
  const int m0 = blockIdx.y * 128;

  const int frow = tid >> 2;          // 0..127 (fill row)
  const int fko = (tid & 3) << 4;     // k offset 0/16/32/48
  const bool bok = (n0 + frow) < NV;
  const uint4 zz = make_uint4(0, 0, 0, 0);

  f32x4 acc[2][4];
#pragma unroll
  for (int i = 0; i < 2; ++i)
#pragma unroll
    for (int j = 0; j < 4; ++j) acc[i][j] = (f32x4){0.f, 0.f, 0.f, 0.f};

  for (int k0 = 0; k0 < 1024; k0 += 64) {
    {  // A fill: 128 rows x 64 k bf16, 32B per thread
      const uint4* s = (const uint4*)(A + (size_t)(m0 + frow) * 1024 + k0 + fko);
      uint4* d = (uint4*)&As[frow * 72 + fko];
      d[0] = s[0];
      d[1] = s[1];
    }
    {  // B fill from Wt rows (n-major, k-contiguous)
      uint4 v0 = zz, v1 = zz;
      if (bok) {
        const uint4* s =
            (const uint4*)(Bt + (size_t)(n0 + frow) * 1024 + k0 + fko);
        v0 = s[0];
        v1 = s[1];
      }
      uint4* d = (uint4*)&Bs[frow * 72 + fko];
      d[0] = v0;
      d[1] = v1;
    }
    __syncthreads();
#pragma unroll
    for (int ks = 0; ks < 64; ks += 32) {
      short8 a[2], b[4];
#pragma unroll
      for (int fm = 0; fm < 2; ++fm)
        a[fm] = *(const short8*)&As[(wm * 32 + fm * 16 + (lane & 15)) * 72 +
                                    ks + ((lane >> 4) << 3)];
#pragma unroll
      for (int fn = 0; fn < 4; ++fn)
        b[fn] = *(const short8*)&Bs[(wn * 64 + fn * 16 + (lane & 15)) * 72 +
                                    ks + ((lane >> 4) << 3)];
#pragma unroll
      for (int fm = 0; fm < 2; ++fm)
#pragma unroll
        for (int fn = 0; fn < 4; ++fn)
          acc[fm][fn] = __builtin_amdgcn_mfma_f32_16x16x32_bf16(
              a[fm], b[fn], acc[fm][fn], 0, 0, 0);
    }
    __syncthreads();
  }

#pragma unroll
  for (int fm = 0; fm < 2; ++fm) {
#pragma unroll
    for (int fn = 0; fn < 4; ++fn) {
      const int col = n0 + wn * 64 + fn * 16 + (lane & 15);
      if (col < NV) {
        const int rbase = m0 + wm * 32 + fm * 16 + ((lane >> 4) << 2);
#pragma unroll
        for (int r = 0; r < 4; ++r)
          C[(size_t)(rbase + r) * NV + col] = acc[fm][fn][r];
      }
    }
  }
}

// ---------------------------------------------------------------------------
// fp32 GEMM, 128x128 tile, BK=16, 256 threads, 8x8 microtile.
//   BT=1: C[M,N] = Amap[M,K] * B[N,K]^T + bias   (input projections)
//   BT=0: C[M,N] = A[M,K]   * B[K,N]   (+bias)   (vocab fallback)
// rowmode: 0 identity, 1 decoder shift (row m -> max(m-1,0)), 2 fixed row.
// ---------------------------------------------------------------------------
#define GBM 128
#define GBN 128
#define GBK 16
#define GLDS 132

template <int BT>
__global__ __launch_bounds__(256) void gemm128(
    const float* __restrict__ A, const float* __restrict__ B,
    const float* __restrict__ bias, float* __restrict__ C, int M, int N, int K,
    int rowmode, int fixedrow) {
  __shared__ float As[GBK][GLDS];
  __shared__ float Bs[GBK][GLDS];
  const int tid = threadIdx.x;
  const int n0 = blockIdx.x * GBN;
  const int m0 = blockIdx.y * GBM;
  const int tx = tid & 15;
  const int ty = tid >> 4;
  float acc[8][8];
#pragma unroll
  for (int i = 0; i < 8; ++i)
#pragma unroll
    for (int j = 0; j < 8; ++j) acc[i][j] = 0.f;

  const int fl = tid >> 1;
  const int fk = (tid & 1) << 3;
  const int am = m0 + fl;
  int asrow = am;
  if (rowmode == 1) asrow = (am == 0) ? 0 : am - 1;
  else if (rowmode == 2) asrow = fixedrow;
  const bool aok = (am < M);
  const bool nfull = (n0 + GBN <= N);

  for (int k0 = 0; k0 < K; k0 += GBK) {
    {
      float4 v0 = make_float4(0.f, 0.f, 0.f, 0.f), v1 = v0;
      if (aok) {
        const float* p = A + (size_t)asrow * K + k0 + fk;
        v0 = *(const float4*)p;
        v1 = *(const float4*)(p + 4);
      }
      As[fk + 0][fl] = v0.x; As[fk + 1][fl] = v0.y;
      As[fk + 2][fl] = v0.z; As[fk + 3][fl] = v0.w;
      As[fk + 4][fl] = v1.x; As[fk + 5][fl] = v1.y;
      As[fk + 6][fl] = v1.z; As[fk + 7][fl] = v1.w;
    }
    if (BT) {
      const int bn = n0 + fl;
      float4 v0 = make_float4(0.f, 0.f, 0.f, 0.f), v1 = v0;
      if (bn < N) {
        const float* p = B + (size_t)bn * K + k0 + fk;
        v0 = *(const float4*)p;
        v1 = *(const float4*)(p + 4);
      }
      Bs[fk + 0][fl] = v0.x; Bs[fk + 1][fl] = v0.y;
      Bs[fk + 2][fl] = v0.z; Bs[fk + 3][fl] = v0.w;
      Bs[fk + 4][fl] = v1.x; Bs[fk + 5][fl] = v1.y;
      Bs[fk + 6][fl] = v1.z; Bs[fk + 7][fl] = v1.w;
    } else {
      const int kl = tid >> 4;
      const int nq = (tid & 15) << 3;
      const float* p = B + (size_t)(k0 + kl) * N + n0 + nq;
      if (nfull) {
        *(float4*)&Bs[kl][nq] = *(const float4*)p;
        *(float4*)&Bs[kl][nq + 4] = *(const float4*)(p + 4);
      } else {
#pragma unroll
        for (int j = 0; j < 8; ++j)
          Bs[kl][nq + j] = (n0 + nq + j < N) ? p[j] : 0.f;
      }
    }
    __syncthreads();
#pragma unroll
    for (int k = 0; k < GBK; ++k) {
      const float4 a0 = *(const float4*)&As[k][ty << 3];
      const float4 a1 = *(const float4*)&As[k][(ty << 3) + 4];
      const float4 b0 = *(const float4*)&Bs[k][tx << 3];
      const float4 b1 = *(const float4*)&Bs[k][(tx << 3) + 4];
      const float av[8] = {a0.x, a0.y, a0.z, a0.w, a1.x, a1.y, a1.z, a1.w};
      const float bv[8] = {b0.x, b0.y, b0.z, b0.w, b1.x, b1.y, b1.z, b1.w};
#pragma unroll
      for (int i = 0; i < 8; ++i)
#pragma unroll
        for (int j = 0; j < 8; ++j) acc[i][j] += av[i] * bv[j];
    }
    __syncthreads();
  }

  const int mb = m0 + (ty << 3);
  const int nb = n0 + (tx << 3);
#pragma unroll
  for (int i = 0; i < 8; ++i) {
    const int m = mb + i;
    if (m >= M) continue;
    float o[8];
#pragma unroll
    for (int j = 0; j < 8; ++j) o[j] = acc[i][j];
    if (nfull) {
      if (bias) {
#pragma unroll
        for (int j = 0; j < 8; ++j) o[j] += bias[nb + j];
      }
      *(float4*)&C[(size_t)m * N + nb] = make_float4(o[0], o[1], o[2], o[3]);
      *(float4*)&C[(size_t)m * N + nb + 4] = make_float4(o[4], o[5], o[6], o[7]);
    } else {
#pragma unroll
      for (int j = 0; j < 8; ++j) {
        const int n = nb + j;
        if (n < N) C[(size_t)m * N + n] = o[j] + (bias ? bias[n] : 0.f);
      }
    }
  }
}

// ---------------------------------------------------------------------------
// Workspace layout (byte offsets):
//   0         fwbuf  u64[1024]        (zeroed each launch)
//   8192      decbuf u64[2048]        (zeroed each launch)
//   24576     gxbw   f32[1536]
//   30720     gxfw   f32[512*1536]
//   3176448   gxdec  f32[1024*3072]
//   15759360  dec_hs f32[1024*1024]  UNION  dec_hs_bf16 u16 (bf16 path)
//   19953664  Wt bf16 u16[28996*1024]  -> end 79337472 (~79.3 MB)
// bf16 path requires ws_size >= 79337472; else fp32 fallback (<20 MB).
// ---------------------------------------------------------------------------
extern "C" void kernel_launch(void* const* d_in, const int* in_sizes, int n_in,
                              void* d_out, int out_size, void* d_ws,
                              size_t ws_size, hipStream_t stream) {
  (void)in_sizes; (void)n_in; (void)out_size;
  const float* input_context  = (const float*)d_in[0];
  const float* output_context = (const float*)d_in[1];
  const float* fw_wih = (const float*)d_in[2];
  const float* fw_whh = (const float*)d_in[3];
  const float* fw_bih = (const float*)d_in[4];
  const float* fw_bhh = (const float*)d_in[5];
  const float* bw_wih = (const float*)d_in[6];
  const float* bw_bih = (const float*)d_in[8];
  const float* bw_bhh = (const float*)d_in[9];
  const float* dec_wih = (const float*)d_in[10];
  const float* dec_whh = (const float*)d_in[11];
  const float* dec_bih = (const float*)d_in[12];
  const float* dec_bhh = (const float*)d_in[13];
  const float* W_pred  = (const float*)d_in[14];
  float* out = (float*)d_out;

  char* wsb = (char*)d_ws;
  u64* fwbuf   = (u64*)wsb;
  u64* decbuf  = (u64*)(wsb + 8192);
  float* gxbw  = (float*)(wsb + 24576);
  float* gxfw  = (float*)(wsb + 30720);
  float* gxdec = (float*)(wsb + 3176448);
  float* dec_hs = (float*)(wsb + 15759360);
  ushort_t* dec_hs_bf = (ushort_t*)(wsb + 15759360);  // union with dec_hs
  ushort_t* Wt = (ushort_t*)(wsb + 19953664);
  const int do_bf16 = (ws_size >= 79337472u) ? 1 : 0;

  // zero the (tag,h) buffers: tag=0 (= ready only for t=0), h0=0
  hipMemsetAsync(d_ws, 0, 24576, stream);

  const dim3 blk(256);
  gemm128<1><<<dim3(12, 4), blk, 0, stream>>>(
      input_context, fw_wih, fw_bih, gxfw, 512, 1536, 768, 0, 0);
  gemm128<1><<<dim3(12, 1), blk, 0, stream>>>(
      input_context, bw_wih, bw_bih, gxbw, 1, 1536, 768, 2, 511);
  gemm128<1><<<dim3(24, 8), blk, 0, stream>>>(
      output_context, dec_wih, dec_bih, gxdec, 1024, 3072, 768, 1, 0);
  if (do_bf16)
    wt_transpose<<<dim3(454, 16), blk, 0, stream>>>(W_pred, Wt);

  recur_kernel<<<dim3(NWG), dim3(NT), 0, stream>>>(
      gxfw, gxdec, gxbw, fw_whh, fw_bhh, dec_whh, dec_bhh, bw_bhh,
      fwbuf, decbuf, dec_hs, dec_hs_bf, do_bf16);

  if (do_bf16)
    gemm_vocab_bf16<<<dim3(227, 8), dim3(512), 0, stream>>>(
        dec_hs_bf, Wt, out);
  else
    gemm128<0><<<dim3(227, 8), blk, 0, stream>>>(
        dec_hs, W_pred, nullptr, out, 1024, NV, 1024, 0, 0);
}

// Round 9
// 5201.427 us; speedup vs baseline: 1.5560x; 1.5560x over previous
//
#include <hip/hip_runtime.h>
#include <math.h>

// ---------------------------------------------------------------------------
// Sizes: input_context[512][768] output_context[1024][768]
// fw_wih[1536][768] fw_whh[1536][512]; dec_wih[3072][768] dec_whh[3072][1024]
// W_pred[1024][28996] -> out[1024][28996] f32
// ---------------------------------------------------------------------------

typedef unsigned long long u64;
typedef unsigned short ushort_t;
typedef __attribute__((ext_vector_type(8))) short short8;
typedef __attribute__((ext_vector_type(4))) float f32x4;

#define NV 28996
#define NRWG 64    // recurrence wgs
#define NWORK 192  // worker wgs
#define GXT 192    // gxdec tiles (24 x 8)
#define TRT 7264   // transpose tiles (454 x 16)
#define VOCT 1816  // vocab tiles (227 cols x 8 row-blocks)

__device__ __forceinline__ float sigmoidf_(float x) {
  return 1.0f / (1.0f + __expf(-x));
}
__device__ __forceinline__ float tanhf_(float x) {
  const float xx = fminf(fmaxf(x, -15.0f), 15.0f);
  const float e = __expf(2.0f * xx);
  return (e - 1.0f) / (e + 1.0f);
}
__device__ __forceinline__ ushort_t f2bf(float f) {
  union { float f; unsigned u; } c; c.f = f;
  unsigned u = c.u;
  u += 0x7fffu + ((u >> 16) & 1u);  // RNE
  return (ushort_t)(u >> 16);
}

__device__ __forceinline__ u64 pack_ht(float h, unsigned tag) {
  union { float f; unsigned u; } c; c.f = h;
  return ((u64)tag << 32) | (u64)c.u;
}
__device__ __forceinline__ float pk_h(u64 v) {
  union { unsigned u; float f; } c; c.u = (unsigned)v; return c.f;
}
__device__ __forceinline__ void astore(u64* p, u64 v) {
  __hip_atomic_store(p, v, __ATOMIC_RELAXED, __HIP_MEMORY_SCOPE_AGENT);
}
__device__ __forceinline__ u64 aload(const u64* p) {
  return __hip_atomic_load((u64*)p, __ATOMIC_RELAXED, __HIP_MEMORY_SCOPE_AGENT);
}
__device__ __forceinline__ void astore32(unsigned* p, unsigned v) {
  __hip_atomic_store(p, v, __ATOMIC_RELAXED, __HIP_MEMORY_SCOPE_AGENT);
}
__device__ __forceinline__ unsigned aload32(const unsigned* p) {
  return __hip_atomic_load((unsigned*)p, __ATOMIC_RELAXED, __HIP_MEMORY_SCOPE_AGENT);
}
__device__ __forceinline__ void afadd32(unsigned* p, unsigned v) {
  __hip_atomic_fetch_add(p, v, __ATOMIC_RELAXED, __HIP_MEMORY_SCOPE_AGENT);
}
__device__ __forceinline__ u64 packf2(float a, float b) {
  union { float f; unsigned u; } ca, cb; ca.f = a; cb.f = b;
  return ((u64)cb.u << 32) | (u64)ca.u;
}

// ===========================================================================
// MEGA KERNEL: wgs 0..63 = R2-protocol recurrence; wgs 64..255 = workers.
//
// Visibility within one kernel (per-XCD L2s not coherent):
//  * fused-produced buffers (gxdec, Wt, dec_hs_bf) are WRITTEN with relaxed
//    agent-scope atomics (write-through to coherence point).
//  * gate counters (gx_done / tr_done / progress) are stored AFTER a
//    __syncthreads (compiler drains vmcnt before s_barrier -> all the wg's
//    atomic data stores reached the coherence point first).
//  * readers first-touch gated lines only after passing the gate, so their
//    local caches hold no stale in-kernel copies.
// Deadlock-free: grid 256 <= resident capacity (all wgs co-resident);
// dependency order recur.dec <- workers.P1 (unconditional),
// workers.P3 <- recur.dec, P1 strictly precedes P3 in program order.
// ===========================================================================
__global__ __launch_bounds__(512) void recur_fused(
    const float* __restrict__ gxfw,    // [512][1536]
    const float* __restrict__ gxdec,   // [1024][3072] (worker-written, fused)
    const float* __restrict__ gxbw,    // [1536]
    const float* __restrict__ whh_fw,  // [1536][512]
    const float* __restrict__ bhh_fw,  // [1536]
    const float* __restrict__ whh_dec, // [3072][1024]
    const float* __restrict__ bhh_dec, // [3072]
    const float* __restrict__ bhh_bw,  // [1536]
    u64* fwbuf,                        // [2][512]  zeroed
    u64* decbuf,                       // [2][1024] zeroed
    unsigned* progress,                // [64] zeroed: dec rows < p visible
    unsigned* gx_done,                 // zeroed
    unsigned* tr_done,                 // zeroed
    float* dec_hs,                     // f32 (fallback path)
    unsigned* dec_hs_b32,              // [1024][512] u32 = 2 bf16 (fused)
    const float* __restrict__ output_context,  // [1024][768]
    const float* __restrict__ dec_wih, // [3072][768]
    const float* __restrict__ dec_bih, // [3072]
    const float* __restrict__ W_pred,  // [1024][NV]
    ushort_t* Wt,                      // [NV][1024] bf16 (worker-written)
    float* __restrict__ outC,          // [1024][NV]
    float* gxdec_w,                    // alias of gxdec (atomic writes)
    int do_bf16, int gx_expected)
{
  __shared__ __align__(16) char SMEM[36864];
  const int tid = threadIdx.x;
  const int wg = blockIdx.x;
  const int wave = tid >> 6;
  const int lane = tid & 63;

  if (wg < NRWG) {
    // ================= RECURRENCE (faithful R2 protocol) =================
    float* Hs = (float*)SMEM;  // 2048 floats ping-pong

    // backward "encoder": one GRU cell on row 511 from h0=0 (gh = bhh)
    if (wg == 0) {
      const int j = tid;
      const float r = sigmoidf_(gxbw[j] + bhh_bw[j]);
      const float z = sigmoidf_(gxbw[512 + j] + bhh_bw[512 + j]);
      const float n = tanhf_(gxbw[1024 + j] + r * bhh_bw[1024 + j]);
      astore(&decbuf[512 + j], pack_ht((1.0f - z) * n, 512u));
    }

    // ---------------- forward encoder: 512 steps ----------------
    {
      const int u = (wg << 3) + wave;
      const float br = bhh_fw[u], bz = bhh_fw[512 + u], bn = bhh_fw[1024 + u];
      float4 wr[3][2];
#pragma unroll
      for (int g = 0; g < 3; ++g) {
        const float* w = whh_fw + (size_t)(g * 512 + u) * 512;
#pragma unroll
        for (int i = 0; i < 2; ++i)
          wr[g][i] = *(const float4*)&w[(i << 8) + (lane << 2)];
      }
      for (int t = 0; t < 512; ++t) {
        const u64* src = fwbuf + ((t & 1) << 9);
        float* hs = Hs + ((t & 1) << 9);
        if (wave == 0) {  // poll + stage into LDS
          u64 v[8];
          for (;;) {
            bool ok = true;
#pragma unroll
            for (int j = 0; j < 8; ++j) {
              v[j] = aload(src + (j << 6) + lane);
              ok &= ((unsigned)(v[j] >> 32) >= (unsigned)t);
            }
            if (__all(ok)) break;
          }
#pragma unroll
          for (int j = 0; j < 8; ++j) hs[(j << 6) + lane] = pk_h(v[j]);
        }
        const float* gx = gxfw + (size_t)t * 1536;
        const float g0 = gx[u], g1 = gx[512 + u], g2 = gx[1024 + u];
        __syncthreads();
        const float4 ha = *(const float4*)&hs[lane << 2];
        const float4 hb = *(const float4*)&hs[256 + (lane << 2)];
        float p0 = wr[0][0].x * ha.x + wr[0][0].y * ha.y + wr[0][0].z * ha.z +
                   wr[0][0].w * ha.w + wr[0][1].x * hb.x + wr[0][1].y * hb.y +
                   wr[0][1].z * hb.z + wr[0][1].w * hb.w;
        float p1 = wr[1][0].x * ha.x + wr[1][0].y * ha.y + wr[1][0].z * ha.z +
                   wr[1][0].w * ha.w + wr[1][1].x * hb.x + wr[1][1].y * hb.y +
                   wr[1][1].z * hb.z + wr[1][1].w * hb.w;
        float p2 = wr[2][0].x * ha.x + wr[2][0].y * ha.y + wr[2][0].z * ha.z +
                   wr[2][0].w * ha.w + wr[2][1].x * hb.x + wr[2][1].y * hb.y +
                   wr[2][1].z * hb.z + wr[2][1].w * hb.w;
#pragma unroll
        for (int s = 1; s < 64; s <<= 1) {
          p0 += __shfl_xor(p0, s, 64);
          p1 += __shfl_xor(p1, s, 64);
          p2 += __shfl_xor(p2, s, 64);
        }
        if (lane == 0) {
          const float hold = hs[u];
          const float r = sigmoidf_(g0 + p0 + br);
          const float z = sigmoidf_(g1 + p1 + bz);
          const float n = tanhf_(g2 + r * (p2 + bn));
          const float hnew = (1.0f - z) * n + z * hold;
          if (t < 511)
            astore(fwbuf + (((t + 1) & 1) << 9) + u,
                   pack_ht(hnew, (unsigned)(t + 1)));
          else
            astore(decbuf + u, pack_ht(hnew, 512u));
        }
      }
    }
    __syncthreads();  // LDS handoff fw -> dec
    // gate: gxdec fully written by workers (one-time; workers finish early)
    if (tid == 0 && gx_expected) {
      while (aload32(gx_done) < (unsigned)gx_expected)
        __builtin_amdgcn_s_sleep(8);
    }
    __syncthreads();

    // ---------------- decoder: 1024 steps ----------------
    {
      const int u0 = (wg << 4) + (wave << 1);
      float bb0[2], bb1[2], bb2[2];
      float4 wr[2][3][4];
#pragma unroll
      for (int uu = 0; uu < 2; ++uu) {
        bb0[uu] = bhh_dec[u0 + uu];
        bb1[uu] = bhh_dec[1024 + u0 + uu];
        bb2[uu] = bhh_dec[2048 + u0 + uu];
#pragma unroll
        for (int g = 0; g < 3; ++g) {
          const float* w = whh_dec + (size_t)(g * 1024 + u0 + uu) * 1024;
#pragma unroll
          for (int i = 0; i < 4; ++i)
            wr[uu][g][i] = *(const float4*)&w[(i << 8) + (lane << 2)];
        }
      }
      for (int td = 0; td < 1024; ++td) {
        const int t = 512 + td;
        const u64* src = decbuf + ((t & 1) << 10);
        float* hs = (float*)SMEM + ((t & 1) << 10);
        if (wave == 0) {
          u64 v[16];
          for (;;) {
            bool ok = true;
#pragma unroll
            for (int j = 0; j < 16; ++j) {
              v[j] = aload(src + (j << 6) + lane);
              ok &= ((unsigned)(v[j] >> 32) >= (unsigned)t);
            }
            if (__all(ok)) break;
          }
#pragma unroll
          for (int j = 0; j < 16; ++j) hs[(j << 6) + lane] = pk_h(v[j]);
        }
        const float* gx = gxdec + (size_t)td * 3072;
        float ga[2], gb[2], gc[2];
#pragma unroll
        for (int uu = 0; uu < 2; ++uu) {
          ga[uu] = gx[u0 + uu];
          gb[uu] = gx[1024 + u0 + uu];
          gc[uu] = gx[2048 + u0 + uu];
        }
        __syncthreads();
        // progress[wg]=td: all waves' step-(td-1) stores were drained at this
        // barrier (vmcnt(0) before s_barrier) -> rows < td at coherence point
        if (wave == 7 && lane == 0 && td)
          astore32(progress + wg, (unsigned)td);
        float4 h4[4];
#pragma unroll
        for (int i = 0; i < 4; ++i)
          h4[i] = *(const float4*)&hs[(i << 8) + (lane << 2)];
        float hn0v = 0.f, hn1v = 0.f;
#pragma unroll
        for (int uu = 0; uu < 2; ++uu) {
          float p0 = 0.f, p1 = 0.f, p2 = 0.f;
#pragma unroll
          for (int i = 0; i < 4; ++i) {
            p0 += wr[uu][0][i].x * h4[i].x + wr[uu][0][i].y * h4[i].y +
                  wr[uu][0][i].z * h4[i].z + wr[uu][0][i].w * h4[i].w;
            p1 += wr[uu][1][i].x * h4[i].x + wr[uu][1][i].y * h4[i].y +
                  wr[uu][1][i].z * h4[i].z + wr[uu][1][i].w * h4[i].w;
            p2 += wr[uu][2][i].x * h4[i].x + wr[uu][2][i].y * h4[i].y +
                  wr[uu][2][i].z * h4[i].z + wr[uu][2][i].w * h4[i].w;
          }
#pragma unroll
          for (int s = 1; s < 64; s <<= 1) {
            p0 += __shfl_xor(p0, s, 64);
            p1 += __shfl_xor(p1, s, 64);
            p2 += __shfl_xor(p2, s, 64);
          }
          if (lane == 0) {
            const int u = u0 + uu;
            const float hold = hs[u];
            const float r = sigmoidf_(ga[uu] + p0 + bb0[uu]);
            const float z = sigmoidf_(gb[uu] + p1 + bb1[uu]);
            const float n = tanhf_(gc[uu] + r * (p2 + bb2[uu]));
            const float hnew = (1.0f - z) * n + z * hold;
            astore(decbuf + (((t + 1) & 1) << 10) + u,
                   pack_ht(hnew, (unsigned)(t + 1)));
            if (uu == 0) hn0v = hnew; else hn1v = hnew;
          }
        }
        if (lane == 0) {  // output row (atomic u32 -> coherent for workers)
          if (do_bf16) {
            const unsigned pk =
                (unsigned)f2bf(hn0v) | ((unsigned)f2bf(hn1v) << 16);
            astore32(&dec_hs_b32[(size_t)td * 512 + (u0 >> 1)], pk);
          } else {
            dec_hs[(size_t)td * 1024 + u0] = hn0v;
            dec_hs[(size_t)td * 1024 + u0 + 1] = hn1v;
          }
        }
      }
      __syncthreads();
      if (wave == 7 && lane == 0) astore32(progress + wg, 1024u);
    }
    return;
  }

  // ========================== WORKERS ==========================
  if (!do_bf16) return;
  const int wid = wg - NRWG;  // 0..191

  // ---- P1: one gxdec 128x128 tile each (rowmode=1 shifted A rows) ----
  {
    float (*As)[132] = (float(*)[132])SMEM;
    float (*Bs)[132] = (float(*)[132])(SMEM + 16 * 132 * 4);
    const int cb = wid % 24, rb = wid / 24;
    const int n0 = cb * 128, m0 = rb * 128;
    float acc[8][8];
    if (tid < 256) {
#pragma unroll
      for (int i = 0; i < 8; ++i)
#pragma unroll
        for (int j = 0; j < 8; ++j) acc[i][j] = 0.f;
    }
    const int fl = tid >> 1, fk = (tid & 1) << 3;
    const int am = m0 + fl;
    const int asrow = (am == 0) ? 0 : am - 1;  // decoder input shift
    for (int k0 = 0; k0 < 768; k0 += 16) {
      if (tid < 256) {
        {
          const float* p = output_context + (size_t)asrow * 768 + k0 + fk;
          const float4 v0 = *(const float4*)p;
          const float4 v1 = *(const float4*)(p + 4);
          As[fk + 0][fl] = v0.x; As[fk + 1][fl] = v0.y;
          As[fk + 2][fl] = v0.z; As[fk + 3][fl] = v0.w;
          As[fk + 4][fl] = v1.x; As[fk + 5][fl] = v1.y;
          As[fk + 6][fl] = v1.z; As[fk + 7][fl] = v1.w;
        }
        {
          const float* p = dec_wih + (size_t)(n0 + fl) * 768 + k0 + fk;
          const float4 v0 = *(const float4*)p;
          const float4 v1 = *(const float4*)(p + 4);
          Bs[fk + 0][fl] = v0.x; Bs[fk + 1][fl] = v0.y;
          Bs[fk + 2][fl] = v0.z; Bs[fk + 3][fl] = v0.w;
          Bs[fk + 4][fl] = v1.x; Bs[fk + 5][fl] = v1.y;
          Bs[fk + 6][fl] = v1.z; Bs[fk + 7][fl] = v1.w;
        }
      }
      __syncthreads();
      if (tid < 256) {
        const int tx = tid & 15, ty = tid >> 4;
#pragma unroll
        for (int k = 0; k < 16; ++k) {
          const float4 a0 = *(const float4*)&As[k][ty << 3];
          const float4 a1 = *(const float4*)&As[k][(ty << 3) + 4];
          const float4 b0 = *(const float4*)&Bs[k][tx << 3];
          const float4 b1 = *(const float4*)&Bs[k][(tx << 3) + 4];
          const float av[8] = {a0.x, a0.y, a0.z, a0.w, a1.x, a1.y, a1.z, a1.w};
          const float bv[8] = {b0.x, b0.y, b0.z, b0.w, b1.x, b1.y, b1.z, b1.w};
#pragma unroll
          for (int i = 0; i < 8; ++i)
#pragma unroll
            for (int j = 0; j < 8; ++j) acc[i][j] += av[i] * bv[j];
        }
      }
      __syncthreads();
    }
    if (tid < 256) {
      const int tx = tid & 15, ty = tid >> 4;
      const int mb = m0 + (ty << 3), nb = n0 + (tx << 3);
#pragma unroll
      for (int i = 0; i < 8; ++i) {
        const int m = mb + i;
#pragma unroll
        for (int j = 0; j < 8; j += 2) {  // coherent u64 (2xf32) stores
          const float oa = acc[i][j] + dec_bih[nb + j];
          const float ob = acc[i][j + 1] + dec_bih[nb + j + 1];
          astore((u64*)&gxdec_w[(size_t)m * 3072 + nb + j], packf2(oa, ob));
        }
      }
    }
    __syncthreads();                       // drain all waves' tile stores
    if (tid == 0) afadd32(gx_done, 1u);    // then count
  }

  // ---- P2: W_pred transpose+bf16 tiles (64x64), strided over workers ----
  {
    float (*T)[65] = (float(*)[65])SMEM;
    for (int i = wid; i < TRT; i += NWORK) {
      const int n0 = (i % 454) * 64;
      const int k0 = (i / 454) * 64;
      __syncthreads();  // LDS reuse
      if (tid < 256) {
        const int nloc = tid & 63, q = tid >> 6;
        const bool nok = (n0 + nloc) < NV;
#pragma unroll
        for (int r = 0; r < 16; ++r) {
          const int kloc = q + r * 4;
          T[kloc][nloc] =
              nok ? W_pred[(size_t)(k0 + kloc) * NV + n0 + nloc] : 0.f;
        }
      }
      __syncthreads();
      if (tid < 256) {
        const int nloc = tid >> 2;           // 0..63
        const int jb = (tid & 3) << 3;       // 8 u32 each
        if (n0 + nloc < NV) {
          unsigned* dst =
              (unsigned*)Wt + (size_t)(n0 + nloc) * 512 + (k0 >> 1) + jb;
#pragma unroll
          for (int j = 0; j < 8; ++j) {
            const int kk = (jb + j) << 1;
            const unsigned pk = (unsigned)f2bf(T[kk][nloc]) |
                                ((unsigned)f2bf(T[kk + 1][nloc]) << 16);
            astore32(dst + j, pk);
          }
        }
      }
    }
    __syncthreads();                      // drain Wt stores
    if (tid == 0) afadd32(tr_done, 1u);   // this worker's share done
  }

  // ---- P3: vocab GEMM tiles, chasing decoder progress ----
  {
    if (wave == 0) {  // all Wt written?
      if (lane == 0)
        while (aload32(tr_done) < (unsigned)NWORK) __builtin_amdgcn_s_sleep(64);
    }
    __syncthreads();
    short* As = (short*)SMEM;
    short* Bs = As + 128 * 72;
    const ushort_t* A = (const ushort_t*)dec_hs_b32;
    const int wm = (tid >> 6) >> 1, wn = (tid >> 6) & 1;
    for (int i = wid; i < VOCT; i += NWORK) {
      const int rb = i / 227, cb = i % 227;
      // wait until dec rows < (rb+1)*128 are visible
      const unsigned tgt = (unsigned)(rb * 128 + 128);
      if (wave == 0) {
        for (;;) {
          const unsigned p = aload32(progress + lane);  // 64 entries
          if (__all(p >= tgt)) break;
          __builtin_amdgcn_s_sleep(64);
        }
      }
      __syncthreads();
      const int n0 = cb * 128, m0 = rb * 128;
      const int frow = tid >> 2;
      const int fko = (tid & 3) << 4;
      const bool bok = (n0 + frow) < NV;
      f32x4 acc[2][4];
#pragma unroll
      for (int a = 0; a < 2; ++a)
#pragma unroll
        for (int b = 0; b < 4; ++b) acc[a][b] = (f32x4){0.f, 0.f, 0.f, 0.f};
      for (int k0 = 0; k0 < 1024; k0 += 64) {
        {
          const uint4* s =
              (const uint4*)(A + (size_t)(m0 + frow) * 1024 + k0 + fko);
          uint4* d = (uint4*)&As[frow * 72 + fko];
          d[0] = s[0]; d[1] = s[1];
        }
        {
          uint4 v0 = make_uint4(0, 0, 0, 0), v1 = v0;
          if (bok) {
            const uint4* s =
                (const uint4*)(Wt + (size_t)(n0 + frow) * 1024 + k0 + fko);
            v0 = s[0]; v1 = s[1];
          }
          uint4* d = (uint4*)&Bs[frow * 72 + fko];
          d[0] = v0; d[1] = v1;
        }
        __syncthreads();
#pragma unroll
        for (int ks = 0; ks < 64; ks += 32) {
          short8 a[2], b[4];
#pragma unroll
          for (int fm = 0; fm < 2; ++fm)
            a[fm] = *(const short8*)&As[(wm * 32 + fm * 16 + (lane & 15)) * 72 +
                                        ks + ((lane >> 4) << 3)];
#pragma unroll
          for (int fn = 0; fn < 4; ++fn)
            b[fn] = *(const short8*)&Bs[(wn * 64 + fn * 16 + (lane & 15)) * 72 +
                                        ks + ((lane >> 4) << 3)];
#pragma unroll
          for (int fm = 0; fm < 2; ++fm)
#pragma unroll
            for (int fn = 0; fn < 4; ++fn)
              acc[fm][fn] = __builtin_amdgcn_mfma_f32_16x16x32_bf16(
                  a[fm], b[fn], acc[fm][fn], 0, 0, 0);
        }
        __syncthreads();
      }
#pragma unroll
      for (int fm = 0; fm < 2; ++fm) {
#pragma unroll
        for (int fn = 0; fn < 4; ++fn) {
          const int col = n0 + wn * 64 + fn * 16 + (lane & 15);
          if (col < NV) {
            const int rbase = m0 + wm * 32 + fm * 16 + ((lane >> 4) << 2);
#pragma unroll
            for (int r = 0; r < 4; ++r)
              outC[(size_t)(rbase + r) * NV + col] = acc[fm][fn][r];
          }
        }
      }
    }
  }
}

// ---------------------------------------------------------------------------
// fp32 GEMM (prologue projections + fallback), 128x128 tile, 256 threads.
// ---------------------------------------------------------------------------
#define GBK 16
#define GLDS 132

template <int BT>
__global__ __launch_bounds__(256) void gemm128(
    const float* __restrict__ A, const float* __restrict__ B,
    const float* __restrict__ bias, float* __restrict__ C, int M, int N, int K,
    int rowmode, int fixedrow) {
  __shared__ float As[GBK][GLDS];
  __shared__ float Bs[GBK][GLDS];
  const int tid = threadIdx.x;
  const int n0 = blockIdx.x * 128;
  const int m0 = blockIdx.y * 128;
  const int tx = tid & 15;
  const int ty = tid >> 4;
  float acc[8][8];
#pragma unroll
  for (int i = 0; i < 8; ++i)
#pragma unroll
    for (int j = 0; j < 8; ++j) acc[i][j] = 0.f;

  const int fl = tid >> 1;
  const int fk = (tid & 1) << 3;
  const int am = m0 + fl;
  int asrow = am;
  if (rowmode == 1) asrow = (am == 0) ? 0 : am - 1;
  else if (rowmode == 2) asrow = fixedrow;
  const bool aok = (am < M);
  const bool nfull = (n0 + 128 <= N);

  for (int k0 = 0; k0 < K; k0 += GBK) {
    {
      float4 v0 = make_float4(0.f, 0.f, 0.f, 0.f), v1 = v0;
      if (aok) {
        const float* p = A + (size_t)asrow * K + k0 + fk;
        v0 = *(const float4*)p;
        v1 = *(const float4*)(p + 4);
      }
      As[fk + 0][fl] = v0.x; As[fk + 1][fl] = v0.y;
      As[fk + 2][fl] = v0.z; As[fk + 3][fl] = v0.w;
      As[fk + 4][fl] = v1.x; As[fk + 5][fl] = v1.y;
      As[fk + 6][fl] = v1.z; As[fk + 7][fl] = v1.w;
    }
    if (BT) {
      const int bn = n0 + fl;
      float4 v0 = make_float4(0.f, 0.f, 0.f, 0.f), v1 = v0;
      if (bn < N) {
        const float* p = B + (size_t)bn * K + k0 + fk;
        v0 = *(const float4*)p;
        v1 = *(const float4*)(p + 4);
      }
      Bs[fk + 0][fl] = v0.x; Bs[fk + 1][fl] = v0.y;
      Bs[fk + 2][fl] = v0.z; Bs[fk + 3][fl] = v0.w;
      Bs[fk + 4][fl] = v1.x; Bs[fk + 5][fl] = v1.y;
      Bs[fk + 6][fl] = v1.z; Bs[fk + 7][fl] = v1.w;
    } else {
      const int kl = tid >> 4;
      const int nq = (tid & 15) << 3;
      const float* p = B + (size_t)(k0 + kl) * N + n0 + nq;
      if (nfull) {
        *(float4*)&Bs[kl][nq] = *(const float4*)p;
        *(float4*)&Bs[kl][nq + 4] = *(const float4*)(p + 4);
      } else {
#pragma unroll
        for (int j = 0; j < 8; ++j)
          Bs[kl][nq + j] = (n0 + nq + j < N) ? p[j] : 0.f;
      }
    }
    __syncthreads();
#pragma unroll
    for (int k = 0; k < GBK; ++k) {
      const float4 a0 = *(const float4*)&As[k][ty << 3];
      const float4 a1 = *(const float4*)&As[k][(ty << 3) + 4];
      const float4 b0 = *(const float4*)&Bs[k][tx << 3];
      const float4 b1 = *(const float4*)&Bs[k][(tx << 3) + 4];
      const float av[8] = {a0.x, a0.y, a0.z, a0.w, a1.x, a1.y, a1.z, a1.w};
      const float bv[8] = {b0.x, b0.y, b0.z, b0.w, b1.x, b1.y, b1.z, b1.w};
#pragma unroll
      for (int i = 0; i < 8; ++i)
#pragma unroll
        for (int j = 0; j < 8; ++j) acc[i][j] += av[i] * bv[j];
    }
    __syncthreads();
  }

  const int mb = m0 + (ty << 3);
  const int nb = n0 + (tx << 3);
#pragma unroll
  for (int i = 0; i < 8; ++i) {
    const int m = mb + i;
    if (m >= M) continue;
    float o[8];
#pragma unroll
    for (int j = 0; j < 8; ++j) o[j] = acc[i][j];
    if (nfull) {
      if (bias) {
#pragma unroll
        for (int j = 0; j < 8; ++j) o[j] += bias[nb + j];
      }
      *(float4*)&C[(size_t)m * N + nb] = make_float4(o[0], o[1], o[2], o[3]);
      *(float4*)&C[(size_t)m * N + nb + 4] = make_float4(o[4], o[5], o[6], o[7]);
    } else {
#pragma unroll
      for (int j = 0; j < 8; ++j) {
        const int n = nb + j;
        if (n < N) C[(size_t)m * N + n] = o[j] + (bias ? bias[n] : 0.f);
      }
    }
  }
}

// ---------------------------------------------------------------------------
// Workspace (byte offsets):
//   0         fwbuf u64[1024]            (zeroed)
//   8192      decbuf u64[2048]           (zeroed)
//   24576     progress u32[64]; gx_done @+256; tr_done @+260  (zeroed)
//   25088     gxbw f32[1536]
//   31232     gxfw f32[512*1536]
//   3176960   gxdec f32[1024*3072]
//   15759872  dec_hs f32 (fallback) / dec_hs_b32 u32[1024*512] (fused)
//   19954176  Wt bf16[28996*1024]  -> end 79337984 (~79.3 MB)
// ---------------------------------------------------------------------------
extern "C" void kernel_launch(void* const* d_in, const int* in_sizes, int n_in,
                              void* d_out, int out_size, void* d_ws,
                              size_t ws_size, hipStream_t stream) {
  (void)in_sizes; (void)n_in; (void)out_size;
  const float* input_context  = (const float*)d_in[0];
  const float* output_context = (const float*)d_in[1];
  const float* fw_wih = (const float*)d_in[2];
  const float* fw_whh = (const float*)d_in[3];
  const float* fw_bih = (const float*)d_in[4];
  const float* fw_bhh = (const float*)d_in[5];
  const float* bw_wih = (const float*)d_in[6];
  const float* bw_bih = (const float*)d_in[8];
  const float* bw_bhh = (const float*)d_in[9];
  const float* dec_wih = (const float*)d_in[10];
  const float* dec_whh = (const float*)d_in[11];
  const float* dec_bih = (const float*)d_in[12];
  const float* dec_bhh = (const float*)d_in[13];
  const float* W_pred  = (const float*)d_in[14];
  float* out = (float*)d_out;

  char* wsb = (char*)d_ws;
  u64* fwbuf   = (u64*)wsb;
  u64* decbuf  = (u64*)(wsb + 8192);
  unsigned* progress = (unsigned*)(wsb + 24576);
  unsigned* gx_done  = (unsigned*)(wsb + 24576 + 256);
  unsigned* tr_done  = (unsigned*)(wsb + 24576 + 260);
  float* gxbw  = (float*)(wsb + 25088);
  float* gxfw  = (float*)(wsb + 31232);
  float* gxdec = (float*)(wsb + 3176960);
  float* dec_hs = (float*)(wsb + 15759872);
  unsigned* dec_hs_b32 = (unsigned*)(wsb + 15759872);
  ushort_t* Wt = (ushort_t*)(wsb + 19954176);
  const int do_bf16 = (ws_size >= 79337984u) ? 1 : 0;

  // zero sync state: (tag,h) buffers + progress/counters
  hipMemsetAsync(d_ws, 0, 25088, stream);

  const dim3 blk(256);
  gemm128<1><<<dim3(12, 4), blk, 0, stream>>>(
      input_context, fw_wih, fw_bih, gxfw, 512, 1536, 768, 0, 0);
  gemm128<1><<<dim3(12, 1), blk, 0, stream>>>(
      input_context, bw_wih, bw_bih, gxbw, 1, 1536, 768, 2, 511);
  if (!do_bf16)  // fallback: gxdec sequentially (workers won't run)
    gemm128<1><<<dim3(24, 8), blk, 0, stream>>>(
        output_context, dec_wih, dec_bih, gxdec, 1024, 3072, 768, 1, 0);

  const int grid = do_bf16 ? (NRWG + NWORK) : NRWG;
  recur_fused<<<dim3(grid), dim3(512), 0, stream>>>(
      gxfw, gxdec, gxbw, fw_whh, fw_bhh, dec_whh, dec_bhh, bw_bhh,
      fwbuf, decbuf, progress, gx_done, tr_done, dec_hs, dec_hs_b32,
      output_context, dec_wih, dec_bih, W_pred, Wt, out, gxdec,
      do_bf16, do_bf16 ? NWORK : 0);

  if (!do_bf16)
    gemm128<0><<<dim3(227, 8), blk, 0, stream>>>(
        dec_hs, W_pred, nullptr, out, 1024, NV, 1024, 0, 0);
}

// Round 10
// 4980.043 us; speedup vs baseline: 1.6251x; 1.0445x over previous
//
#include <hip/hip_runtime.h>
#include <math.h>

// ---------------------------------------------------------------------------
// Sizes: input_context[512][768] output_context[1024][768]
// fw_wih[1536][768] fw_whh[1536][512]; dec_wih[3072][768] dec_whh[3072][1024]
// W_pred[1024][28996] -> out[1024][28996] f32
// ---------------------------------------------------------------------------

typedef unsigned long long u64;
typedef unsigned short ushort_t;
typedef __attribute__((ext_vector_type(8))) short short8;
typedef __attribute__((ext_vector_type(4))) float f32x4;

#define NV 28996
#define NRWG 64    // recurrence wgs
#define NWORK 192  // worker wgs
#define TRT 7264   // transpose tiles (454 x 16)
#define VOCT 1816  // vocab tiles (227 cols x 8 row-blocks)

__device__ __forceinline__ float sigmoidf_(float x) {
  return 1.0f / (1.0f + __expf(-x));
}
__device__ __forceinline__ float tanhf_(float x) {
  const float xx = fminf(fmaxf(x, -15.0f), 15.0f);
  const float e = __expf(2.0f * xx);
  return (e - 1.0f) / (e + 1.0f);
}
__device__ __forceinline__ ushort_t f2bf(float f) {
  union { float f; unsigned u; } c; c.f = f;
  unsigned u = c.u;
  u += 0x7fffu + ((u >> 16) & 1u);  // RNE
  return (ushort_t)(u >> 16);
}

__device__ __forceinline__ u64 pack_ht(float h, unsigned tag) {
  union { float f; unsigned u; } c; c.f = h;
  return ((u64)tag << 32) | (u64)c.u;
}
__device__ __forceinline__ float pk_h(u64 v) {
  union { unsigned u; float f; } c; c.u = (unsigned)v; return c.f;
}
__device__ __forceinline__ void astore(u64* p, u64 v) {
  __hip_atomic_store(p, v, __ATOMIC_RELAXED, __HIP_MEMORY_SCOPE_AGENT);
}
__device__ __forceinline__ u64 aload(const u64* p) {
  return __hip_atomic_load((u64*)p, __ATOMIC_RELAXED, __HIP_MEMORY_SCOPE_AGENT);
}
__device__ __forceinline__ void astore32(unsigned* p, unsigned v) {
  __hip_atomic_store(p, v, __ATOMIC_RELAXED, __HIP_MEMORY_SCOPE_AGENT);
}
__device__ __forceinline__ unsigned aload32(const unsigned* p) {
  return __hip_atomic_load((unsigned*)p, __ATOMIC_RELAXED, __HIP_MEMORY_SCOPE_AGENT);
}
__device__ __forceinline__ void afadd32(unsigned* p, unsigned v) {
  __hip_atomic_fetch_add(p, v, __ATOMIC_RELAXED, __HIP_MEMORY_SCOPE_AGENT);
}
__device__ __forceinline__ u64 packf2(float a, float b) {
  union { float f; unsigned u; } ca, cb; ca.f = a; cb.f = b;
  return ((u64)cb.u << 32) | (u64)ca.u;
}

// ===========================================================================
// MEGA KERNEL: wgs 0..63 = recurrence (R2 protocol); wgs 64..255 = workers.
// NEW vs R9: recurrence wgs self-compute their private gxfw slice into LDS
// (kills the gxfw prologue GEMM and per-step global gx reads) and each wg
// computes+publishes its OWN 8 backward-cell outputs (kills the gxbw GEMM;
// zero cross-wg dependency: wg g owns exactly the bw_wih rows it needs).
// Visibility/deadlock arguments unchanged from R9 (comments there).
// ===========================================================================
__global__ __launch_bounds__(512) void recur_fused(
    const float* __restrict__ input_context,   // [512][768]
    const float* __restrict__ fw_wih,  // [1536][768]
    const float* __restrict__ fw_bih,  // [1536]
    const float* __restrict__ bw_wih,  // [1536][768]
    const float* __restrict__ bw_bih,  // [1536]
    const float* __restrict__ bhh_bw,  // [1536]
    const float* __restrict__ gxdec,   // [1024][3072] (worker-written)
    const float* __restrict__ whh_fw,  // [1536][512]
    const float* __restrict__ bhh_fw,  // [1536]
    const float* __restrict__ whh_dec, // [3072][1024]
    const float* __restrict__ bhh_dec, // [3072]
    u64* fwbuf,                        // [2][512]  zeroed
    u64* decbuf,                       // [2][1024] zeroed
    unsigned* progress,                // [64] zeroed
    unsigned* gx_done,                 // zeroed
    unsigned* tr_done,                 // zeroed
    float* dec_hs,                     // f32 (fallback path)
    unsigned* dec_hs_b32,              // [1024][512] u32 = 2 bf16 (fused)
    const float* __restrict__ output_context,  // [1024][768]
    const float* __restrict__ dec_wih, // [3072][768]
    const float* __restrict__ dec_bih, // [3072]
    const float* __restrict__ W_pred,  // [1024][NV]
    ushort_t* Wt,                      // [NV][1024] bf16 (worker-written)
    float* __restrict__ outC,          // [1024][NV]
    float* gxdec_w,                    // alias of gxdec (atomic writes)
    int do_bf16, int gx_expected)
{
  __shared__ __align__(16) char SMEM[57344];
  const int tid = threadIdx.x;
  const int wg = blockIdx.x;
  const int wave = tid >> 6;
  const int lane = tid & 63;

  if (wg < NRWG) {
    // ============== RECURRENCE ==============
    float* Hs = (float*)SMEM;            // [0,8192): h ping-pong
    float* gxs = (float*)(SMEM + 8192);  // [8192,57344): gxfw slice [512][24]
    const int u0 = wg << 3;

    // ---- Phase S: self-compute gxfw slice (24 cols x 512 rows) into LDS ----
    {
      const int r = (wave << 6) + lane;  // this lane's input row, 0..511
      const float* inrow = input_context + (size_t)r * 768;
      const float* wbase = fw_wih + (size_t)u0 * 768;
      float acc[24];
#pragma unroll
      for (int c = 0; c < 24; ++c) acc[c] = 0.f;
      for (int k = 0; k < 768; k += 4) {
        const float4 in4 = *(const float4*)&inrow[k];
#pragma unroll
        for (int u8 = 0; u8 < 8; ++u8) {
#pragma unroll
          for (int g = 0; g < 3; ++g) {
            // weight addr = wave-uniform (broadcast across lanes)
            const float4 w4 =
                *(const float4*)&wbase[(size_t)(g * 512 + u8) * 768 + k];
            acc[u8 * 3 + g] +=
                w4.x * in4.x + w4.y * in4.y + w4.z * in4.z + w4.w * in4.w;
          }
        }
      }
#pragma unroll
      for (int u8 = 0; u8 < 8; ++u8)
#pragma unroll
        for (int g = 0; g < 3; ++g)
          gxs[r * 24 + u8 * 3 + g] =
              acc[u8 * 3 + g] + fw_bih[g * 512 + u0 + u8];
    }
    // ---- Phase S2: this wg's 8 backward-cell outputs (self-contained) ----
    {
      const int u = u0 + wave;
      const float* in511 = input_context + (size_t)511 * 768;
      float b0 = 0.f, b1 = 0.f, b2 = 0.f;
      for (int k = lane; k < 768; k += 64) {
        const float x = in511[k];
        b0 += x * bw_wih[(size_t)u * 768 + k];
        b1 += x * bw_wih[(size_t)(512 + u) * 768 + k];
        b2 += x * bw_wih[(size_t)(1024 + u) * 768 + k];
      }
#pragma unroll
      for (int s = 1; s < 64; s <<= 1) {
        b0 += __shfl_xor(b0, s, 64);
        b1 += __shfl_xor(b1, s, 64);
        b2 += __shfl_xor(b2, s, 64);
      }
      if (lane == 0) {
        const float r = sigmoidf_(b0 + bw_bih[u] + bhh_bw[u]);
        const float z = sigmoidf_(b1 + bw_bih[512 + u] + bhh_bw[512 + u]);
        const float n =
            tanhf_(b2 + bw_bih[1024 + u] + r * bhh_bw[1024 + u]);
        astore(&decbuf[512 + u], pack_ht((1.0f - z) * n, 512u));
      }
    }
    __syncthreads();  // gxs ready

    // ---------------- forward encoder: 512 steps ----------------
    {
      const int u = u0 + wave;
      const float br = bhh_fw[u], bz = bhh_fw[512 + u], bn = bhh_fw[1024 + u];
      float4 wr[3][2];
#pragma unroll
      for (int g = 0; g < 3; ++g) {
        const float* w = whh_fw + (size_t)(g * 512 + u) * 512;
#pragma unroll
        for (int i = 0; i < 2; ++i)
          wr[g][i] = *(const float4*)&w[(i << 8) + (lane << 2)];
      }
      for (int t = 0; t < 512; ++t) {
        const u64* src = fwbuf + ((t & 1) << 9);
        float* hs = Hs + ((t & 1) << 9);
        if (wave == 0) {  // poll + stage into LDS
          u64 v[8];
          for (;;) {
            bool ok = true;
#pragma unroll
            for (int j = 0; j < 8; ++j) {
              v[j] = aload(src + (j << 6) + lane);
              ok &= ((unsigned)(v[j] >> 32) >= (unsigned)t);
            }
            if (__all(ok)) break;
          }
#pragma unroll
          for (int j = 0; j < 8; ++j) hs[(j << 6) + lane] = pk_h(v[j]);
        }
        // gx from LDS slice (broadcast reads, off critical path)
        const float g0 = gxs[t * 24 + wave * 3 + 0];
        const float g1 = gxs[t * 24 + wave * 3 + 1];
        const float g2 = gxs[t * 24 + wave * 3 + 2];
        __syncthreads();
        const float4 ha = *(const float4*)&hs[lane << 2];
        const float4 hb = *(const float4*)&hs[256 + (lane << 2)];
        float p0 = wr[0][0].x * ha.x + wr[0][0].y * ha.y + wr[0][0].z * ha.z +
                   wr[0][0].w * ha.w + wr[0][1].x * hb.x + wr[0][1].y * hb.y +
                   wr[0][1].z * hb.z + wr[0][1].w * hb.w;
        float p1 = wr[1][0].x * ha.x + wr[1][0].y * ha.y + wr[1][0].z * ha.z +
                   wr[1][0].w * ha.w + wr[1][1].x * hb.x + wr[1][1].y * hb.y +
                   wr[1][1].z * hb.z + wr[1][1].w * hb.w;
        float p2 = wr[2][0].x * ha.x + wr[2][0].y * ha.y + wr[2][0].z * ha.z +
                   wr[2][0].w * ha.w + wr[2][1].x * hb.x + wr[2][1].y * hb.y +
                   wr[2][1].z * hb.z + wr[2][1].w * hb.w;
#pragma unroll
        for (int s = 1; s < 64; s <<= 1) {
          p0 += __shfl_xor(p0, s, 64);
          p1 += __shfl_xor(p1, s, 64);
          p2 += __shfl_xor(p2, s, 64);
        }
        if (lane == 0) {
          const float hold = hs[u];
          const float r = sigmoidf_(g0 + p0 + br);
          const float z = sigmoidf_(g1 + p1 + bz);
          const float n = tanhf_(g2 + r * (p2 + bn));
          const float hnew = (1.0f - z) * n + z * hold;
          if (t < 511)
            astore(fwbuf + (((t + 1) & 1) << 9) + u,
                   pack_ht(hnew, (unsigned)(t + 1)));
          else
            astore(decbuf + u, pack_ht(hnew, 512u));
        }
      }
    }
    __syncthreads();  // LDS handoff fw -> dec
    if (tid == 0 && gx_expected) {  // gxdec fully written by workers
      while (aload32(gx_done) < (unsigned)gx_expected)
        __builtin_amdgcn_s_sleep(8);
    }
    __syncthreads();

    // ---------------- decoder: 1024 steps ----------------
    {
      const int du0 = (wg << 4) + (wave << 1);
      float bb0[2], bb1[2], bb2[2];
      float4 wr[2][3][4];
#pragma unroll
      for (int uu = 0; uu < 2; ++uu) {
        bb0[uu] = bhh_dec[du0 + uu];
        bb1[uu] = bhh_dec[1024 + du0 + uu];
        bb2[uu] = bhh_dec[2048 + du0 + uu];
#pragma unroll
        for (int g = 0; g < 3; ++g) {
          const float* w = whh_dec + (size_t)(g * 1024 + du0 + uu) * 1024;
#pragma unroll
          for (int i = 0; i < 4; ++i)
            wr[uu][g][i] = *(const float4*)&w[(i << 8) + (lane << 2)];
        }
      }
      for (int td = 0; td < 1024; ++td) {
        const int t = 512 + td;
        const u64* src = decbuf + ((t & 1) << 10);
        float* hs = (float*)SMEM + ((t & 1) << 10);
        if (wave == 0) {
          u64 v[16];
          for (;;) {
            bool ok = true;
#pragma unroll
            for (int j = 0; j < 16; ++j) {
              v[j] = aload(src + (j << 6) + lane);
              ok &= ((unsigned)(v[j] >> 32) >= (unsigned)t);
            }
            if (__all(ok)) break;
          }
#pragma unroll
          for (int j = 0; j < 16; ++j) hs[(j << 6) + lane] = pk_h(v[j]);
        }
        const float* gx = gxdec + (size_t)td * 3072;
        float ga[2], gb[2], gc[2];
#pragma unroll
        for (int uu = 0; uu < 2; ++uu) {
          ga[uu] = gx[du0 + uu];
          gb[uu] = gx[1024 + du0 + uu];
          gc[uu] = gx[2048 + du0 + uu];
        }
        __syncthreads();
        if (wave == 7 && lane == 0 && td)
          astore32(progress + wg, (unsigned)td);
        float4 h4[4];
#pragma unroll
        for (int i = 0; i < 4; ++i)
          h4[i] = *(const float4*)&hs[(i << 8) + (lane << 2)];
        float hn0v = 0.f, hn1v = 0.f;
#pragma unroll
        for (int uu = 0; uu < 2; ++uu) {
          float p0 = 0.f, p1 = 0.f, p2 = 0.f;
#pragma unroll
          for (int i = 0; i < 4; ++i) {
            p0 += wr[uu][0][i].x * h4[i].x + wr[uu][0][i].y * h4[i].y +
                  wr[uu][0][i].z * h4[i].z + wr[uu][0][i].w * h4[i].w;
            p1 += wr[uu][1][i].x * h4[i].x + wr[uu][1][i].y * h4[i].y +
                  wr[uu][1][i].z * h4[i].z + wr[uu][1][i].w * h4[i].w;
            p2 += wr[uu][2][i].x * h4[i].x + wr[uu][2][i].y * h4[i].y +
                  wr[uu][2][i].z * h4[i].z + wr[uu][2][i].w * h4[i].w;
          }
#pragma unroll
          for (int s = 1; s < 64; s <<= 1) {
            p0 += __shfl_xor(p0, s, 64);
            p1 += __shfl_xor(p1, s, 64);
            p2 += __shfl_xor(p2, s, 64);
          }
          if (lane == 0) {
            const int u = du0 + uu;
            const float hold = hs[u];
            const float r = sigmoidf_(ga[uu] + p0 + bb0[uu]);
            const float z = sigmoidf_(gb[uu] + p1 + bb1[uu]);
            const float n = tanhf_(gc[uu] + r * (p2 + bb2[uu]));
            const float hnew = (1.0f - z) * n + z * hold;
            astore(decbuf + (((t + 1) & 1) << 10) + u,
                   pack_ht(hnew, (unsigned)(t + 1)));
            if (uu == 0) hn0v = hnew; else hn1v = hnew;
          }
        }
        if (lane == 0) {
          if (do_bf16) {
            const unsigned pk =
                (unsigned)f2bf(hn0v) | ((unsigned)f2bf(hn1v) << 16);
            astore32(&dec_hs_b32[(size_t)td * 512 + (du0 >> 1)], pk);
          } else {
            dec_hs[(size_t)td * 1024 + du0] = hn0v;
            dec_hs[(size_t)td * 1024 + du0 + 1] = hn1v;
          }
        }
      }
      __syncthreads();
      if (wave == 7 && lane == 0) astore32(progress + wg, 1024u);
    }
    return;
  }

  // ========================== WORKERS ==========================
  if (!do_bf16) return;
  const int wid = wg - NRWG;  // 0..191

  // ---- P1: one gxdec 128x128 tile each (rowmode=1 shifted A rows) ----
  {
    float (*As)[132] = (float(*)[132])SMEM;
    float (*Bs)[132] = (float(*)[132])(SMEM + 16 * 132 * 4);
    const int cb = wid % 24, rb = wid / 24;
    const int n0 = cb * 128, m0 = rb * 128;
    float acc[8][8];
    if (tid < 256) {
#pragma unroll
      for (int i = 0; i < 8; ++i)
#pragma unroll
        for (int j = 0; j < 8; ++j) acc[i][j] = 0.f;
    }
    const int fl = tid >> 1, fk = (tid & 1) << 3;
    const int am = m0 + fl;
    const int asrow = (am == 0) ? 0 : am - 1;  // decoder input shift
    for (int k0 = 0; k0 < 768; k0 += 16) {
      if (tid < 256) {
        {
          const float* p = output_context + (size_t)asrow * 768 + k0 + fk;
          const float4 v0 = *(const float4*)p;
          const float4 v1 = *(const float4*)(p + 4);
          As[fk + 0][fl] = v0.x; As[fk + 1][fl] = v0.y;
          As[fk + 2][fl] = v0.z; As[fk + 3][fl] = v0.w;
          As[fk + 4][fl] = v1.x; As[fk + 5][fl] = v1.y;
          As[fk + 6][fl] = v1.z; As[fk + 7][fl] = v1.w;
        }
        {
          const float* p = dec_wih + (size_t)(n0 + fl) * 768 + k0 + fk;
          const float4 v0 = *(const float4*)p;
          const float4 v1 = *(const float4*)(p + 4);
          Bs[fk + 0][fl] = v0.x; Bs[fk + 1][fl] = v0.y;
          Bs[fk + 2][fl] = v0.z; Bs[fk + 3][fl] = v0.w;
          Bs[fk + 4][fl] = v1.x; Bs[fk + 5][fl] = v1.y;
          Bs[fk + 6][fl] = v1.z; Bs[fk + 7][fl] = v1.w;
        }
      }
      __syncthreads();
      if (tid < 256) {
        const int tx = tid & 15, ty = tid >> 4;
#pragma unroll
        for (int k = 0; k < 16; ++k) {
          const float4 a0 = *(const float4*)&As[k][ty << 3];
          const float4 a1 = *(const float4*)&As[k][(ty << 3) + 4];
          const float4 b0 = *(const float4*)&Bs[k][tx << 3];
          const float4 b1 = *(const float4*)&Bs[k][(tx << 3) + 4];
          const float av[8] = {a0.x, a0.y, a0.z, a0.w, a1.x, a1.y, a1.z, a1.w};
          const float bv[8] = {b0.x, b0.y, b0.z, b0.w, b1.x, b1.y, b1.z, b1.w};
#pragma unroll
          for (int i = 0; i < 8; ++i)
#pragma unroll
            for (int j = 0; j < 8; ++j) acc[i][j] += av[i] * bv[j];
        }
      }
      __syncthreads();
    }
    if (tid < 256) {
      const int tx = tid & 15, ty = tid >> 4;
      const int mb = m0 + (ty << 3), nb = n0 + (tx << 3);
#pragma unroll
      for (int i = 0; i < 8; ++i) {
        const int m = mb + i;
#pragma unroll
        for (int j = 0; j < 8; j += 2) {
          const float oa = acc[i][j] + dec_bih[nb + j];
          const float ob = acc[i][j + 1] + dec_bih[nb + j + 1];
          astore((u64*)&gxdec_w[(size_t)m * 3072 + nb + j], packf2(oa, ob));
        }
      }
    }
    __syncthreads();
    if (tid == 0) afadd32(gx_done, 1u);
  }

  // ---- P2: W_pred transpose+bf16 tiles (64x64), strided over workers ----
  {
    float (*T)[65] = (float(*)[65])SMEM;
    for (int i = wid; i < TRT; i += NWORK) {
      const int n0 = (i % 454) * 64;
      const int k0 = (i / 454) * 64;
      __syncthreads();
      if (tid < 256) {
        const int nloc = tid & 63, q = tid >> 6;
        const bool nok = (n0 + nloc) < NV;
#pragma unroll
        for (int r = 0; r < 16; ++r) {
          const int kloc = q + r * 4;
          T[kloc][nloc] =
              nok ? W_pred[(size_t)(k0 + kloc) * NV + n0 + nloc] : 0.f;
        }
      }
      __syncthreads();
      if (tid < 256) {
        const int nloc = tid >> 2;
        const int jb = (tid & 3) << 3;
        if (n0 + nloc < NV) {
          unsigned* dst =
              (unsigned*)Wt + (size_t)(n0 + nloc) * 512 + (k0 >> 1) + jb;
#pragma unroll
          for (int j = 0; j < 8; ++j) {
            const int kk = (jb + j) << 1;
            const unsigned pk = (unsigned)f2bf(T[kk][nloc]) |
                                ((unsigned)f2bf(T[kk + 1][nloc]) << 16);
            astore32(dst + j, pk);
          }
        }
      }
    }
    __syncthreads();
    if (tid == 0) afadd32(tr_done, 1u);
  }

  // ---- P3: vocab GEMM tiles, chasing decoder progress ----
  {
    if (wave == 0) {
      if (lane == 0)
        while (aload32(tr_done) < (unsigned)NWORK) __builtin_amdgcn_s_sleep(64);
    }
    __syncthreads();
    short* As = (short*)SMEM;
    short* Bs = As + 128 * 72;
    const ushort_t* A = (const ushort_t*)dec_hs_b32;
    const int wm = (tid >> 6) >> 1, wn = (tid >> 6) & 1;
    for (int i = wid; i < VOCT; i += NWORK) {
      const int rb = i / 227, cb = i % 227;
      const unsigned tgt = (unsigned)(rb * 128 + 128);
      if (wave == 0) {
        for (;;) {
          const unsigned p = aload32(progress + lane);
          if (__all(p >= tgt)) break;
          __builtin_amdgcn_s_sleep(64);
        }
      }
      __syncthreads();
      const int n0 = cb * 128, m0 = rb * 128;
      const int frow = tid >> 2;
      const int fko = (tid & 3) << 4;
      const bool bok = (n0 + frow) < NV;
      f32x4 acc[2][4];
#pragma unroll
      for (int a = 0; a < 2; ++a)
#pragma unroll
        for (int b = 0; b < 4; ++b) acc[a][b] = (f32x4){0.f, 0.f, 0.f, 0.f};
      for (int k0 = 0; k0 < 1024; k0 += 64) {
        {
          const uint4* s =
              (const uint4*)(A + (size_t)(m0 + frow) * 1024 + k0 + fko);
          uint4* d = (uint4*)&As[frow * 72 + fko];
          d[0] = s[0]; d[1] = s[1];
        }
        {
          uint4 v0 = make_uint4(0, 0, 0, 0), v1 = v0;
          if (bok) {
            const uint4* s =
                (const uint4*)(Wt + (size_t)(n0 + frow) * 1024 + k0 + fko);
            v0 = s[0]; v1 = s[1];
          }
          uint4* d = (uint4*)&Bs[frow * 72 + fko];
          d[0] = v0; d[1] = v1;
        }
        __syncthreads();
#pragma unroll
        for (int ks = 0; ks < 64; ks += 32) {
          short8 a[2], b[4];
#pragma unroll
          for (int fm = 0; fm < 2; ++fm)
            a[fm] = *(const short8*)&As[(wm * 32 + fm * 16 + (lane & 15)) * 72 +
                                        ks + ((lane >> 4) << 3)];
#pragma unroll
          for (int fn = 0; fn < 4; ++fn)
            b[fn] = *(const short8*)&Bs[(wn * 64 + fn * 16 + (lane & 15)) * 72 +
                                        ks + ((lane >> 4) << 3)];
#pragma unroll
          for (int fm = 0; fm < 2; ++fm)
#pragma unroll
            for (int fn = 0; fn < 4; ++fn)
              acc[fm][fn] = __builtin_amdgcn_mfma_f32_16x16x32_bf16(
                  a[fm], b[fn], acc[fm][fn], 0, 0, 0);
        }
        __syncthreads();
      }
#pragma unroll
      for (int fm = 0; fm < 2; ++fm) {
#pragma unroll
        for (int fn = 0; fn < 4; ++fn) {
          const int col = n0 + wn * 64 + fn * 16 + (lane & 15);
          if (col < NV) {
            const int rbase = m0 + wm * 32 + fm * 16 + ((lane >> 4) << 2);
#pragma unroll
            for (int r = 0; r < 4; ++r)
              outC[(size_t)(rbase + r) * NV + col] = acc[fm][fn][r];
          }
        }
      }
    }
  }
}

// ---------------------------------------------------------------------------
// fp32 GEMM (fallback only), 128x128 tile, 256 threads.
// ---------------------------------------------------------------------------
#define GBK 16
#define GLDS 132

template <int BT>
__global__ __launch_bounds__(256) void gemm128(
    const float* __restrict__ A, const float* __restrict__ B,
    const float* __restrict__ bias, float* __restrict__ C, int M, int N, int K,
    int rowmode, int fixedrow) {
  __shared__ float As[GBK][GLDS];
  __shared__ float Bs[GBK][GLDS];
  const int tid = threadIdx.x;
  const int n0 = blockIdx.x * 128;
  const int m0 = blockIdx.y * 128;
  const int tx = tid & 15;
  const int ty = tid >> 4;
  float acc[8][8];
#pragma unroll
  for (int i = 0; i < 8; ++i)
#pragma unroll
    for (int j = 0; j < 8; ++j) acc[i][j] = 0.f;

  const int fl = tid >> 1;
  const int fk = (tid & 1) << 3;
  const int am = m0 + fl;
  int asrow = am;
  if (rowmode == 1) asrow = (am == 0) ? 0 : am - 1;
  else if (rowmode == 2) asrow = fixedrow;
  const bool aok = (am < M);
  const bool nfull = (n0 + 128 <= N);

  for (int k0 = 0; k0 < K; k0 += GBK) {
    {
      float4 v0 = make_float4(0.f, 0.f, 0.f, 0.f), v1 = v0;
      if (aok) {
        const float* p = A + (size_t)asrow * K + k0 + fk;
        v0 = *(const float4*)p;
        v1 = *(const float4*)(p + 4);
      }
      As[fk + 0][fl] = v0.x; As[fk + 1][fl] = v0.y;
      As[fk + 2][fl] = v0.z; As[fk + 3][fl] = v0.w;
      As[fk + 4][fl] = v1.x; As[fk + 5][fl] = v1.y;
      As[fk + 6][fl] = v1.z; As[fk + 7][fl] = v1.w;
    }
    if (BT) {
      const int bn = n0 + fl;
      float4 v0 = make_float4(0.f, 0.f, 0.f, 0.f), v1 = v0;
      if (bn < N) {
        const float* p = B + (size_t)bn * K + k0 + fk;
        v0 = *(const float4*)p;
        v1 = *(const float4*)(p + 4);
      }
      Bs[fk + 0][fl] = v0.x; Bs[fk + 1][fl] = v0.y;
      Bs[fk + 2][fl] = v0.z; Bs[fk + 3][fl] = v0.w;
      Bs[fk + 4][fl] = v1.x; Bs[fk + 5][fl] = v1.y;
      Bs[fk + 6][fl] = v1.z; Bs[fk + 7][fl] = v1.w;
    } else {
      const int kl = tid >> 4;
      const int nq = (tid & 15) << 3;
      const float* p = B + (size_t)(k0 + kl) * N + n0 + nq;
      if (nfull) {
        *(float4*)&Bs[kl][nq] = *(const float4*)p;
        *(float4*)&Bs[kl][nq + 4] = *(const float4*)(p + 4);
      } else {
#pragma unroll
        for (int j = 0; j < 8; ++j)
          Bs[kl][nq + j] = (n0 + nq + j < N) ? p[j] : 0.f;
      }
    }
    __syncthreads();
#pragma unroll
    for (int k = 0; k < GBK; ++k) {
      const float4 a0 = *(const float4*)&As[k][ty << 3];
      const float4 a1 = *(const float4*)&As[k][(ty << 3) + 4];
      const float4 b0 = *(const float4*)&Bs[k][tx << 3];
      const float4 b1 = *(const float4*)&Bs[k][(tx << 3) + 4];
      const float av[8] = {a0.x, a0.y, a0.z, a0.w, a1.x, a1.y, a1.z, a1.w};
      const float bv[8] = {b0.x, b0.y, b0.z, b0.w, b1.x, b1.y, b1.z, b1.w};
#pragma unroll
      for (int i = 0; i < 8; ++i)
#pragma unroll
        for (int j = 0; j < 8; ++j) acc[i][j] += av[i] * bv[j];
    }
    __syncthreads();
  }

  const int mb = m0 + (ty << 3);
  const int nb = n0 + (tx << 3);
#pragma unroll
  for (int i = 0; i < 8; ++i) {
    const int m = mb + i;
    if (m >= M) continue;
    float o[8];
#pragma unroll
    for (int j = 0; j < 8; ++j) o[j] = acc[i][j];
    if (nfull) {
      if (bias) {
#pragma unroll
        for (int j = 0; j < 8; ++j) o[j] += bias[nb + j];
      }
      *(float4*)&C[(size_t)m * N + nb] = make_float4(o[0], o[1], o[2], o[3]);
      *(float4*)&C[(size_t)m * N + nb + 4] = make_float4(o[4], o[5], o[6], o[7]);
    } else {
#pragma unroll
      for (int j = 0; j < 8; ++j) {
        const int n = nb + j;
        if (n < N) C[(size_t)m * N + n] = o[j] + (bias ? bias[n] : 0.f);
      }
    }
  }
}

// ---------------------------------------------------------------------------
// Workspace (byte offsets) — unchanged from R9 for safety:
//   0         fwbuf u64[1024]            (zeroed)
//   8192      decbuf u64[2048]           (zeroed)
//   24576     progress u32[64]; gx_done @+256; tr_done @+260  (zeroed)
//   3176960   gxdec f32[1024*3072]
//   15759872  dec_hs f32 (fallback) / dec_hs_b32 u32[1024*512] (fused)
//   19954176  Wt bf16[28996*1024]  -> end 79337984 (~79.3 MB)
// ---------------------------------------------------------------------------
extern "C" void kernel_launch(void* const* d_in, const int* in_sizes, int n_in,
                              void* d_out, int out_size, void* d_ws,
                              size_t ws_size, hipStream_t stream) {
  (void)in_sizes; (void)n_in; (void)out_size;
  const float* input_context  = (const float*)d_in[0];
  const float* output_context = (const float*)d_in[1];
  const float* fw_wih = (const float*)d_in[2];
  const float* fw_whh = (const float*)d_in[3];
  const float* fw_bih = (const float*)d_in[4];
  const float* fw_bhh = (const float*)d_in[5];
  const float* bw_wih = (const float*)d_in[6];
  const float* bw_bih = (const float*)d_in[8];
  const float* bw_bhh = (const float*)d_in[9];
  const float* dec_wih = (const float*)d_in[10];
  const float* dec_whh = (const float*)d_in[11];
  const float* dec_bih = (const float*)d_in[12];
  const float* dec_bhh = (const float*)d_in[13];
  const float* W_pred  = (const float*)d_in[14];
  float* out = (float*)d_out;

  char* wsb = (char*)d_ws;
  u64* fwbuf   = (u64*)wsb;
  u64* decbuf  = (u64*)(wsb + 8192);
  unsigned* progress = (unsigned*)(wsb + 24576);
  unsigned* gx_done  = (unsigned*)(wsb + 24576 + 256);
  unsigned* tr_done  = (unsigned*)(wsb + 24576 + 260);
  float* gxdec = (float*)(wsb + 3176960);
  float* dec_hs = (float*)(wsb + 15759872);
  unsigned* dec_hs_b32 = (unsigned*)(wsb + 15759872);
  ushort_t* Wt = (ushort_t*)(wsb + 19954176);
  const int do_bf16 = (ws_size >= 79337984u) ? 1 : 0;

  // zero sync state: (tag,h) buffers + progress/counters
  hipMemsetAsync(d_ws, 0, 25088, stream);

  if (!do_bf16)  // fallback: gxdec sequentially (workers won't run)
    gemm128<1><<<dim3(24, 8), dim3(256), 0, stream>>>(
        output_context, dec_wih, dec_bih, gxdec, 1024, 3072, 768, 1, 0);

  const int grid = do_bf16 ? (NRWG + NWORK) : NRWG;
  recur_fused<<<dim3(grid), dim3(512), 0, stream>>>(
      input_context, fw_wih, fw_bih, bw_wih, bw_bih, bw_bhh,
      gxdec, fw_whh, fw_bhh, dec_whh, dec_bhh,
      fwbuf, decbuf, progress, gx_done, tr_done, dec_hs, dec_hs_b32,
      output_context, dec_wih, dec_bih, W_pred, Wt, out, gxdec,
      do_bf16, do_bf16 ? NWORK : 0);

  if (!do_bf16)
    gemm128<0><<<dim3(227, 8), dim3(256), 0, stream>>>(
        dec_hs, W_pred, nullptr, out, 1024, NV, 1024, 0, 0);
}